// Round 8
// baseline (111.723 us; speedup 1.0000x reference)
//
#include <hip/hip_runtime.h>
#include <math.h>

// Problem constants (match reference)
#define BB   16
#define CC   64
#define LL   512
#define LP   16
#define DM   1024
#define NP   64
#define PRD  256   // period = L/2
#define HEAD 128   // PRD/2
#define NV   256   // L - PRD

typedef float f32x4 __attribute__((ext_vector_type(4)));

// workspace layout (in floats); all offsets 16B-aligned
#define OFF_MEANP 0                    // 8192
#define OFF_WSF   8192                 // 16*256 folded seasonal weights
#define OFF_WRS   (8192 + 4096)        // 16 resid weight sums
#define OFF_RES   16384                // 1024*1024 result table (4 MB)

// ---------------------------------------------------------------------------
// Kernel 1: blocks 0..31 = per-(b,l) channel stats; block 32 = weight folding.
// (identical to R6)
// ---------------------------------------------------------------------------
__global__ __launch_bounds__(256) void statsprep_kernel(
    const float* __restrict__ dx, const float* __restrict__ w_s,
    const float* __restrict__ w_r, float* __restrict__ ws)
{
    const int tid = threadIdx.x, bid = blockIdx.x;
    if (bid < 32) {
        int id = bid * 256 + tid;            // 0..8191
        int b = id >> 9, l = id & 511;
        const float* p = dx + (size_t)b * CC * LL + l;
        float s = 0.f, sq = 0.f;
#pragma unroll 8
        for (int c = 0; c < CC; ++c) {
            float v = p[(size_t)c * LL];
            s += v; sq += v * v;
        }
        float mean = s * (1.0f / CC);
        float var  = (sq - (float)CC * mean * mean) * (1.0f / (CC - 1));
        ws[OFF_MEANP + id] = mean / sqrtf(var);
    } else {
        // fold seasonal weights: wsf[g][m] = w_s[g][m] + w_s[g][m+256]
#pragma unroll
        for (int idx = tid; idx < 16 * PRD; idx += 256) {
            int g = idx >> 8, m = idx & 255;
            ws[OFF_WSF + idx] = w_s[g * LL + m] + w_s[g * LL + PRD + m];
        }
        // resid weight sums: wrs[g] = sum w_r[g][128:384]
        int g = tid >> 4, ln = tid & 15;
        float s = 0.f;
        for (int k = ln; k < PRD; k += 16) s += w_r[g * LL + HEAD + k];
#pragma unroll
        for (int m = 8; m; m >>= 1) s += __shfl_xor(s, m, 16);
        if (ln == 0) ws[OFF_WRS + g] = s;
    }
}

// ---------------------------------------------------------------------------
// Kernel 2: one block per (b,c). Transform -> scan decompose -> 48 features
// -> per-thread 4-row matvec vs w_g (L2-hot) -> ONE contiguous 4KB resbuf row.
// NO __launch_bounds__ min-waves (R7 lesson: it forces spills in the matvec).
// ---------------------------------------------------------------------------
__global__ __launch_bounds__(256) void featsmv_kernel(
    const float* __restrict__ dx,    const float* __restrict__ gamma,
    const float* __restrict__ beta,  const float* __restrict__ w_t,
    const float* __restrict__ b_t,   const float* __restrict__ b_s,
    const float* __restrict__ b_r,   const float* __restrict__ w_g,
    const float* __restrict__ b_g,   float* __restrict__ ws)
{
    __shared__ __align__(16) float xs[LL];
    __shared__ __align__(16) float pps[LL/2 + 1];
    __shared__ __align__(16) float tvs[NV];
    __shared__ __align__(16) float pas[PRD];
    __shared__ __align__(16) float feats[48];
    __shared__ float wsum[4];
    __shared__ float wred[4];

    const int tid  = threadIdx.x;
    const int lane = tid & 63;
    const int wv   = tid >> 6;
    const int bc   = blockIdx.x;
    const int b    = bc >> 6;

    // transform (float2): x = gamma*(dx - meanp) + beta
    const size_t base = (size_t)bc * LL;
    float2 xv = ((const float2*)(dx    + base))[tid];
    float2 gv = ((const float2*)(gamma + base))[tid];
    float2 bv = ((const float2*)(beta  + base))[tid];
    float2 mv = ((const float2*)(ws + OFF_MEANP + (size_t)b * LL))[tid];
    float2 xp;
    xp.x = gv.x * (xv.x - mv.x) + bv.x;
    xp.y = gv.y * (xv.y - mv.y) + bv.y;
    ((float2*)xs)[tid] = xp;

    // inclusive scan of pair-sums (256 pairs)
    float v = xp.x + xp.y;
#pragma unroll
    for (int d = 1; d < 64; d <<= 1) {
        float t = __shfl_up(v, d, 64);
        if (lane >= d) v += t;
    }
    if (lane == 63) wsum[wv] = v;
    __syncthreads();
    float off = 0.f;
    for (int w = 0; w < wv; ++w) off += wsum[w];
    pps[tid + 1] = v + off;
    if (tid == 0) pps[0] = 0.f;
    __syncthreads();

    // trend via prefix sums
    const int i  = tid;
    const int k2 = i + 257;
    const float Pi = pps[i  >> 1] + ((i  & 1) ? xs[i  & ~1] : 0.f);
    const float Pk = pps[k2 >> 1] + ((k2 & 1) ? xs[k2 & ~1] : 0.f);
    const float tv = (Pk - Pi - 0.5f * (xs[i] + xs[i + 256])) * (1.0f / 256.0f);
    tvs[i] = tv;
    const float dv = xs[HEAD + i] - tv;

    // mdv = mean(dv)
    float r = dv;
#pragma unroll
    for (int m = 32; m; m >>= 1) r += __shfl_xor(r, m, 64);
    if (lane == 0) wred[wv] = r;
    __syncthreads();
    const float mdv = (wred[0] + wred[1] + wred[2] + wred[3]) * (1.0f / 256.0f);

    pas[(i + 128) & 255] = dv - mdv;
    __syncthreads();

    // feature dots with folded weights (8 float4 loads/thread)
    {
        const int g  = tid >> 4;
        const int ln = tid & 15;
        const f32x4* wt4  = (const f32x4*)(w_t + g * LL + HEAD);
        const f32x4* wsf4 = (const f32x4*)(ws + OFF_WSF + g * PRD);
        const f32x4* tv4  = (const f32x4*)tvs;
        const f32x4* pa4  = (const f32x4*)pas;
        float at = 0.f, as = 0.f;
#pragma unroll
        for (int q = 0; q < 4; ++q) {
            const int m = ln * 4 + q;
            f32x4 t = tv4[m], p = pa4[m];
            f32x4 a = wt4[m], sfw = wsf4[m];
            at += t.x * a.x + t.y * a.y + t.z * a.z + t.w * a.w;
            as += p.x * sfw.x + p.y * sfw.y + p.z * sfw.z + p.w * sfw.w;
        }
#pragma unroll
        for (int msk = 8; msk; msk >>= 1) {
            at += __shfl_xor(at, msk, 64);
            as += __shfl_xor(as, msk, 64);
        }
        if (ln == 0) {
            feats[g]      = at + b_t[g];
            feats[16 + g] = as + b_s[g];
            feats[32 + g] = mdv * ws[OFF_WRS + g] + b_r[g];
        }
    }
    __syncthreads();

    // per-thread matvec: 4 consecutive d rows of w_g (48 floats each)
    f32x4 f[12];
    const f32x4* fr4 = (const f32x4*)feats;
#pragma unroll
    for (int j = 0; j < 12; ++j) f[j] = fr4[j];

    const int d0 = tid * 4;
    const f32x4 bg = ((const f32x4*)b_g)[tid];
    float a[4];
#pragma unroll
    for (int row = 0; row < 4; ++row) {
        const f32x4* wg4 = (const f32x4*)(w_g + (size_t)(d0 + row) * 48);
        float acc = 0.f;
#pragma unroll
        for (int j = 0; j < 12; ++j) {
            f32x4 w = wg4[j];
            acc += f[j].x * w.x + f[j].y * w.y + f[j].z * w.z + f[j].w * w.w;
        }
        a[row] = acc;
    }
    f32x4 res;
    res.x = a[0] + bg.x; res.y = a[1] + bg.y;
    res.z = a[2] + bg.z; res.w = a[3] + bg.w;

    // ONE contiguous 4KB row write per block (vs gemm's strided scalar stores)
    ((f32x4*)(ws + OFF_RES))[(size_t)bc * (DM / 4) + tid] = res;
}

// ---------------------------------------------------------------------------
// Kernel 3: broadcast store (identical to R6). 4096 blocks; block = (bc, q).
// 16 independent PLAIN f32x4 stores per thread, 64 KB per block.
// ---------------------------------------------------------------------------
__global__ __launch_bounds__(256) void bcast_kernel(
    const float* __restrict__ resbuf, float* __restrict__ out)
{
    const int tid = threadIdx.x;
    const int bc  = blockIdx.x >> 2;
    const int q   = blockIdx.x & 3;
    const f32x4 v = ((const f32x4*)resbuf)[bc * (DM / 4) + tid];
    f32x4* op = (f32x4*)out + (size_t)bc * (NP * DM / 4)
              + (size_t)q * 16 * (DM / 4) + tid;
#pragma unroll
    for (int n = 0; n < 16; ++n)
        op[(size_t)n * (DM / 4)] = v;
}

// ---------------------------------------------------------------------------
extern "C" void kernel_launch(void* const* d_in, const int* in_sizes, int n_in,
                              void* d_out, int out_size, void* d_ws, size_t ws_size,
                              hipStream_t stream) {
    const float* dx    = (const float*)d_in[0];
    const float* gamma = (const float*)d_in[1];
    const float* beta  = (const float*)d_in[2];
    const float* w_t   = (const float*)d_in[3];
    const float* b_t   = (const float*)d_in[4];
    const float* w_s   = (const float*)d_in[5];
    const float* b_s   = (const float*)d_in[6];
    const float* w_r   = (const float*)d_in[7];
    const float* b_r   = (const float*)d_in[8];
    const float* w_g   = (const float*)d_in[9];
    const float* b_g   = (const float*)d_in[10];
    float* out = (float*)d_out;
    float* ws  = (float*)d_ws;

    statsprep_kernel<<<33, 256, 0, stream>>>(dx, w_s, w_r, ws);
    featsmv_kernel<<<BB * CC, 256, 0, stream>>>(
        dx, gamma, beta, w_t, b_t, b_s, b_r, w_g, b_g, ws);
    bcast_kernel<<<BB * CC * 4, 256, 0, stream>>>(ws + OFF_RES, out);
}

// Round 9
// 75.450 us; speedup vs baseline: 1.4807x; 1.4807x over previous
//
#include <hip/hip_runtime.h>
#include <math.h>

// Problem constants (match reference)
#define BB   16
#define CC   64
#define LL   512
#define LP   16
#define DM   1024
#define NP   64
#define PRD  256   // period = L/2
#define HEAD 128   // PRD/2
#define NV   256   // L - PRD

typedef float f32x4 __attribute__((ext_vector_type(4)));

// workspace layout (in floats); all offsets 16B-aligned
#define OFF_MEANP 0                       // 8192
#define OFF_WSF   8192                    // 16*256 folded seasonal weights
#define OFF_WRS   12288                   // 16 resid weight sums
#define OFF_WGT   12304                   // 48*1024 transposed w_g
#define OFF_FEATS (12304 + 49152)         // 1024*48 feature rows

// ---------------------------------------------------------------------------
// Kernel 1: blocks 0..31 = per-(b,l) channel stats; block 32 = weight folding;
// blocks 33..48 = w_g transpose ([1024][48] -> [48][1024]).
// ---------------------------------------------------------------------------
__global__ __launch_bounds__(256) void statsprep_kernel(
    const float* __restrict__ dx, const float* __restrict__ w_s,
    const float* __restrict__ w_r, const float* __restrict__ w_g,
    float* __restrict__ ws)
{
    const int tid = threadIdx.x, bid = blockIdx.x;
    if (bid < 32) {
        int id = bid * 256 + tid;            // 0..8191
        int b = id >> 9, l = id & 511;
        const float* p = dx + (size_t)b * CC * LL + l;
        float s = 0.f, sq = 0.f;
#pragma unroll 8
        for (int c = 0; c < CC; ++c) {
            float v = p[(size_t)c * LL];
            s += v; sq += v * v;
        }
        float mean = s * (1.0f / CC);
        float var  = (sq - (float)CC * mean * mean) * (1.0f / (CC - 1));
        ws[OFF_MEANP + id] = mean / sqrtf(var);
    } else if (bid == 32) {
        // fold seasonal weights: wsf[g][m] = w_s[g][m] + w_s[g][m+256]
#pragma unroll
        for (int idx = tid; idx < 16 * PRD; idx += 256) {
            int g = idx >> 8, m = idx & 255;
            ws[OFF_WSF + idx] = w_s[g * LL + m] + w_s[g * LL + PRD + m];
        }
        // resid weight sums: wrs[g] = sum w_r[g][128:384]
        int g = tid >> 4, ln = tid & 15;
        float s = 0.f;
        for (int k = ln; k < PRD; k += 16) s += w_r[g * LL + HEAD + k];
#pragma unroll
        for (int m = 8; m; m >>= 1) s += __shfl_xor(s, m, 16);
        if (ln == 0) ws[OFF_WRS + g] = s;
    } else {
        // transpose w_g: wgt[j*1024 + d] = w_g[d*48 + j]
        int base = (bid - 33) * 3072 + tid;
#pragma unroll
        for (int k = 0; k < 12; ++k) {
            int e = base + k * 256;          // e = j*1024 + d
            int j = e >> 10, d = e & 1023;
            ws[OFF_WGT + e] = w_g[d * 48 + j];
        }
    }
}

// ---------------------------------------------------------------------------
// Kernel 2: one block per (b,c). Transform -> scan decompose -> 48 features.
// (identical to R6's feats kernel)
// ---------------------------------------------------------------------------
__global__ __launch_bounds__(256) void feats_kernel(
    const float* __restrict__ dx,    const float* __restrict__ gamma,
    const float* __restrict__ beta,  const float* __restrict__ w_t,
    const float* __restrict__ b_t,   const float* __restrict__ b_s,
    const float* __restrict__ b_r,   float* __restrict__ ws)
{
    __shared__ __align__(16) float xs[LL];
    __shared__ __align__(16) float pps[LL/2 + 1];
    __shared__ __align__(16) float tvs[NV];
    __shared__ __align__(16) float pas[PRD];
    __shared__ __align__(16) float feats[48];
    __shared__ float wsum[4];
    __shared__ float wred[4];

    const int tid  = threadIdx.x;
    const int lane = tid & 63;
    const int wv   = tid >> 6;
    const int bc   = blockIdx.x;
    const int b    = bc >> 6;

    // transform (float2): x = gamma*(dx - meanp) + beta
    const size_t base = (size_t)bc * LL;
    float2 xv = ((const float2*)(dx    + base))[tid];
    float2 gv = ((const float2*)(gamma + base))[tid];
    float2 bv = ((const float2*)(beta  + base))[tid];
    float2 mv = ((const float2*)(ws + OFF_MEANP + (size_t)b * LL))[tid];
    float2 xp;
    xp.x = gv.x * (xv.x - mv.x) + bv.x;
    xp.y = gv.y * (xv.y - mv.y) + bv.y;
    ((float2*)xs)[tid] = xp;

    // inclusive scan of pair-sums (256 pairs)
    float v = xp.x + xp.y;
#pragma unroll
    for (int d = 1; d < 64; d <<= 1) {
        float t = __shfl_up(v, d, 64);
        if (lane >= d) v += t;
    }
    if (lane == 63) wsum[wv] = v;
    __syncthreads();
    float off = 0.f;
    for (int w = 0; w < wv; ++w) off += wsum[w];
    pps[tid + 1] = v + off;
    if (tid == 0) pps[0] = 0.f;
    __syncthreads();

    // trend via prefix sums
    const int i  = tid;
    const int k2 = i + 257;
    const float Pi = pps[i  >> 1] + ((i  & 1) ? xs[i  & ~1] : 0.f);
    const float Pk = pps[k2 >> 1] + ((k2 & 1) ? xs[k2 & ~1] : 0.f);
    const float tv = (Pk - Pi - 0.5f * (xs[i] + xs[i + 256])) * (1.0f / 256.0f);
    tvs[i] = tv;
    const float dv = xs[HEAD + i] - tv;

    // mdv = mean(dv)
    float r = dv;
#pragma unroll
    for (int m = 32; m; m >>= 1) r += __shfl_xor(r, m, 64);
    if (lane == 0) wred[wv] = r;
    __syncthreads();
    const float mdv = (wred[0] + wred[1] + wred[2] + wred[3]) * (1.0f / 256.0f);

    pas[(i + 128) & 255] = dv - mdv;
    __syncthreads();

    // feature dots with folded weights (8 float4 loads/thread)
    {
        const int g  = tid >> 4;
        const int ln = tid & 15;
        const f32x4* wt4  = (const f32x4*)(w_t + g * LL + HEAD);
        const f32x4* wsf4 = (const f32x4*)(ws + OFF_WSF + g * PRD);
        const f32x4* tv4  = (const f32x4*)tvs;
        const f32x4* pa4  = (const f32x4*)pas;
        float at = 0.f, as = 0.f;
#pragma unroll
        for (int q = 0; q < 4; ++q) {
            const int m = ln * 4 + q;
            f32x4 t = tv4[m], p = pa4[m];
            f32x4 a = wt4[m], sfw = wsf4[m];
            at += t.x * a.x + t.y * a.y + t.z * a.z + t.w * a.w;
            as += p.x * sfw.x + p.y * sfw.y + p.z * sfw.z + p.w * sfw.w;
        }
#pragma unroll
        for (int msk = 8; msk; msk >>= 1) {
            at += __shfl_xor(at, msk, 64);
            as += __shfl_xor(as, msk, 64);
        }
        if (ln == 0) {
            feats[g]      = at + b_t[g];
            feats[16 + g] = as + b_s[g];
            feats[32 + g] = mdv * ws[OFF_WRS + g] + b_r[g];
        }
    }
    __syncthreads();

    // write 48-float feature row
    if (tid < 12)
        ((f32x4*)(ws + OFF_FEATS))[bc * 12 + tid] = ((const f32x4*)feats)[tid];
}

// ---------------------------------------------------------------------------
// Kernel 3: fused matvec + broadcast store. 4096 blocks = (bc, d-slice of 256).
// Coalesced w_gT reads (48 KB/block), LDS re-stage, then 16 x 1KB-per-wave
// f32x4 stores per thread (same store shape as R6's proven bcast).
// ---------------------------------------------------------------------------
__global__ __launch_bounds__(256) void mvbcast_kernel(
    const float* __restrict__ ws, const float* __restrict__ b_g,
    float* __restrict__ out)
{
    __shared__ float sf[48];
    __shared__ __align__(16) float sres[256];

    const int tid = threadIdx.x;
    const int bc  = blockIdx.x >> 2;
    const int q   = blockIdx.x & 3;          // d-slice: d in [q*256, q*256+256)

    if (tid < 48) sf[tid] = ws[OFF_FEATS + bc * 48 + tid];
    __syncthreads();

    const int d = q * 256 + tid;
    const float* wT = ws + OFF_WGT + d;
    float acc = b_g[d];
#pragma unroll
    for (int j = 0; j < 48; ++j)
        acc = fmaf(sf[j], wT[j * 1024], acc);
    sres[tid] = acc;
    __syncthreads();

    const int lane = tid & 63;
    const int wv   = tid >> 6;
    const f32x4 v = ((const f32x4*)sres)[lane];
    // out f32x4 col = q*64 + lane; rows n = wv + 4k, k = 0..15
    f32x4* op = (f32x4*)out + (size_t)bc * (NP * DM / 4)
              + (size_t)wv * (DM / 4) + q * 64 + lane;
#pragma unroll
    for (int k = 0; k < 16; ++k)
        op[(size_t)k * 4 * (DM / 4)] = v;
}

// ---------------------------------------------------------------------------
extern "C" void kernel_launch(void* const* d_in, const int* in_sizes, int n_in,
                              void* d_out, int out_size, void* d_ws, size_t ws_size,
                              hipStream_t stream) {
    const float* dx    = (const float*)d_in[0];
    const float* gamma = (const float*)d_in[1];
    const float* beta  = (const float*)d_in[2];
    const float* w_t   = (const float*)d_in[3];
    const float* b_t   = (const float*)d_in[4];
    const float* w_s   = (const float*)d_in[5];
    const float* b_s   = (const float*)d_in[6];
    const float* w_r   = (const float*)d_in[7];
    const float* b_r   = (const float*)d_in[8];
    const float* w_g   = (const float*)d_in[9];
    const float* b_g   = (const float*)d_in[10];
    float* out = (float*)d_out;
    float* ws  = (float*)d_ws;

    statsprep_kernel<<<49, 256, 0, stream>>>(dx, w_s, w_r, w_g, ws);
    feats_kernel<<<BB * CC, 256, 0, stream>>>(
        dx, gamma, beta, w_t, b_t, b_s, b_r, ws);
    mvbcast_kernel<<<BB * CC * 4, 256, 0, stream>>>(ws, b_g, out);
}

// Round 10
// 66.080 us; speedup vs baseline: 1.6907x; 1.1418x over previous
//
#include <hip/hip_runtime.h>
#include <math.h>

// Problem constants (match reference)
#define BB   16
#define CC   64
#define LL   512
#define LP   16
#define DM   1024
#define NP   64
#define PRD  256   // period = L/2
#define HEAD 128   // PRD/2
#define NV   256   // L - PRD

typedef float f32x4 __attribute__((ext_vector_type(4)));

// workspace layout (in floats); all offsets 16B-aligned
#define OFF_MEANP 0                       // 8192
#define OFF_WSF   8192                    // 16*256 folded seasonal weights
#define OFF_WRS   12288                   // 16 resid weight sums
#define OFF_WGT   12304                   // 48*1024 transposed w_g

// ---------------------------------------------------------------------------
// Kernel 1: blocks 0..31 = per-(b,l) channel stats; block 32 = weight folding;
// blocks 33..48 = w_g transpose ([1024][48] -> [48][1024]). (identical to R9)
// ---------------------------------------------------------------------------
__global__ __launch_bounds__(256) void statsprep_kernel(
    const float* __restrict__ dx, const float* __restrict__ w_s,
    const float* __restrict__ w_r, const float* __restrict__ w_g,
    float* __restrict__ ws)
{
    const int tid = threadIdx.x, bid = blockIdx.x;
    if (bid < 32) {
        int id = bid * 256 + tid;            // 0..8191
        int b = id >> 9, l = id & 511;
        const float* p = dx + (size_t)b * CC * LL + l;
        float s = 0.f, sq = 0.f;
#pragma unroll 8
        for (int c = 0; c < CC; ++c) {
            float v = p[(size_t)c * LL];
            s += v; sq += v * v;
        }
        float mean = s * (1.0f / CC);
        float var  = (sq - (float)CC * mean * mean) * (1.0f / (CC - 1));
        ws[OFF_MEANP + id] = mean / sqrtf(var);
    } else if (bid == 32) {
        // fold seasonal weights: wsf[g][m] = w_s[g][m] + w_s[g][m+256]
#pragma unroll
        for (int idx = tid; idx < 16 * PRD; idx += 256) {
            int g = idx >> 8, m = idx & 255;
            ws[OFF_WSF + idx] = w_s[g * LL + m] + w_s[g * LL + PRD + m];
        }
        // resid weight sums: wrs[g] = sum w_r[g][128:384]
        int g = tid >> 4, ln = tid & 15;
        float s = 0.f;
        for (int k = ln; k < PRD; k += 16) s += w_r[g * LL + HEAD + k];
#pragma unroll
        for (int m = 8; m; m >>= 1) s += __shfl_xor(s, m, 16);
        if (ln == 0) ws[OFF_WRS + g] = s;
    } else {
        // transpose w_g: wgt[j*1024 + d] = w_g[d*48 + j]
        int base = (bid - 33) * 3072 + tid;
#pragma unroll
        for (int k = 0; k < 12; ++k) {
            int e = base + k * 256;          // e = j*1024 + d
            int j = e >> 10, d = e & 1023;
            ws[OFF_WGT + e] = w_g[d * 48 + j];
        }
    }
}

// ---------------------------------------------------------------------------
// Kernel 2 (fused): one block per (b,c). Transform -> scan decompose ->
// 48 features (LDS) -> matvec vs TRANSPOSED w_g (coalesced, L2-hot) ->
// stage 4KB row in LDS -> 64 direct broadcast row-stores.
// NO __launch_bounds__ min-waves hint (R7 lesson).
// ---------------------------------------------------------------------------
__global__ __launch_bounds__(256) void fused_kernel(
    const float* __restrict__ dx,    const float* __restrict__ gamma,
    const float* __restrict__ beta,  const float* __restrict__ w_t,
    const float* __restrict__ b_t,   const float* __restrict__ b_s,
    const float* __restrict__ b_r,   const float* __restrict__ b_g,
    const float* __restrict__ ws,    float* __restrict__ out)
{
    __shared__ __align__(16) float xs[LL];
    __shared__ __align__(16) float pps[LL/2 + 1];
    __shared__ __align__(16) float tvs[NV];
    __shared__ __align__(16) float pas[PRD];
    __shared__ __align__(16) float feats[48];
    __shared__ __align__(16) float sres[DM];      // 4KB result row
    __shared__ float wsum[4];
    __shared__ float wred[4];

    const int tid  = threadIdx.x;
    const int lane = tid & 63;
    const int wv   = tid >> 6;
    const int bc   = blockIdx.x;
    const int b    = bc >> 6;

    // transform (float2): x = gamma*(dx - meanp) + beta
    const size_t base = (size_t)bc * LL;
    float2 xv = ((const float2*)(dx    + base))[tid];
    float2 gv = ((const float2*)(gamma + base))[tid];
    float2 bv = ((const float2*)(beta  + base))[tid];
    float2 mv = ((const float2*)(ws + OFF_MEANP + (size_t)b * LL))[tid];
    float2 xp;
    xp.x = gv.x * (xv.x - mv.x) + bv.x;
    xp.y = gv.y * (xv.y - mv.y) + bv.y;
    ((float2*)xs)[tid] = xp;

    // inclusive scan of pair-sums (256 pairs)
    float v = xp.x + xp.y;
#pragma unroll
    for (int d = 1; d < 64; d <<= 1) {
        float t = __shfl_up(v, d, 64);
        if (lane >= d) v += t;
    }
    if (lane == 63) wsum[wv] = v;
    __syncthreads();
    float off = 0.f;
    for (int w = 0; w < wv; ++w) off += wsum[w];
    pps[tid + 1] = v + off;
    if (tid == 0) pps[0] = 0.f;
    __syncthreads();

    // trend via prefix sums
    const int i  = tid;
    const int k2 = i + 257;
    const float Pi = pps[i  >> 1] + ((i  & 1) ? xs[i  & ~1] : 0.f);
    const float Pk = pps[k2 >> 1] + ((k2 & 1) ? xs[k2 & ~1] : 0.f);
    const float tv = (Pk - Pi - 0.5f * (xs[i] + xs[i + 256])) * (1.0f / 256.0f);
    tvs[i] = tv;
    const float dv = xs[HEAD + i] - tv;

    // mdv = mean(dv)
    float r = dv;
#pragma unroll
    for (int m = 32; m; m >>= 1) r += __shfl_xor(r, m, 64);
    if (lane == 0) wred[wv] = r;
    __syncthreads();
    const float mdv = (wred[0] + wred[1] + wred[2] + wred[3]) * (1.0f / 256.0f);

    pas[(i + 128) & 255] = dv - mdv;
    __syncthreads();

    // feature dots with folded weights (8 float4 loads/thread)
    {
        const int g  = tid >> 4;
        const int ln = tid & 15;
        const f32x4* wt4  = (const f32x4*)(w_t + g * LL + HEAD);
        const f32x4* wsf4 = (const f32x4*)(ws + OFF_WSF + g * PRD);
        const f32x4* tv4  = (const f32x4*)tvs;
        const f32x4* pa4  = (const f32x4*)pas;
        float at = 0.f, as = 0.f;
#pragma unroll
        for (int q = 0; q < 4; ++q) {
            const int m = ln * 4 + q;
            f32x4 t = tv4[m], p = pa4[m];
            f32x4 a = wt4[m], sfw = wsf4[m];
            at += t.x * a.x + t.y * a.y + t.z * a.z + t.w * a.w;
            as += p.x * sfw.x + p.y * sfw.y + p.z * sfw.z + p.w * sfw.w;
        }
#pragma unroll
        for (int msk = 8; msk; msk >>= 1) {
            at += __shfl_xor(at, msk, 64);
            as += __shfl_xor(as, msk, 64);
        }
        if (ln == 0) {
            feats[g]      = at + b_t[g];
            feats[16 + g] = as + b_s[g];
            feats[32 + g] = mdv * ws[OFF_WRS + g] + b_r[g];
        }
    }
    __syncthreads();

    // ---- matvec vs transposed w_g: thread handles d = q*256+tid, q=0..3.
    // Coalesced: per (j,q) a wave reads 256B contiguous; w_gT is L2-hot.
    const float* wT = ws + OFF_WGT;
    float acc0 = b_g[tid];
    float acc1 = b_g[256 + tid];
    float acc2 = b_g[512 + tid];
    float acc3 = b_g[768 + tid];
#pragma unroll
    for (int j = 0; j < 48; ++j) {
        const float fj = feats[j];
        const float* w = wT + j * DM + tid;
        acc0 = fmaf(fj, w[0],   acc0);
        acc1 = fmaf(fj, w[256], acc1);
        acc2 = fmaf(fj, w[512], acc2);
        acc3 = fmaf(fj, w[768], acc3);
    }
    sres[tid]       = acc0;
    sres[256 + tid] = acc1;
    sres[512 + tid] = acc2;
    sres[768 + tid] = acc3;
    __syncthreads();

    // ---- 64 direct broadcast row-stores (each wave-instr = 1KB contiguous)
    const f32x4 res = ((const f32x4*)sres)[tid];
    f32x4* op = (f32x4*)out + (size_t)bc * (NP * DM / 4) + tid;
#pragma unroll
    for (int n = 0; n < NP; ++n)
        op[(size_t)n * (DM / 4)] = res;
}

// ---------------------------------------------------------------------------
extern "C" void kernel_launch(void* const* d_in, const int* in_sizes, int n_in,
                              void* d_out, int out_size, void* d_ws, size_t ws_size,
                              hipStream_t stream) {
    const float* dx    = (const float*)d_in[0];
    const float* gamma = (const float*)d_in[1];
    const float* beta  = (const float*)d_in[2];
    const float* w_t   = (const float*)d_in[3];
    const float* b_t   = (const float*)d_in[4];
    const float* w_s   = (const float*)d_in[5];
    const float* b_s   = (const float*)d_in[6];
    const float* w_r   = (const float*)d_in[7];
    const float* b_r   = (const float*)d_in[8];
    const float* w_g   = (const float*)d_in[9];
    const float* b_g   = (const float*)d_in[10];
    float* out = (float*)d_out;
    float* ws  = (float*)d_ws;

    statsprep_kernel<<<49, 256, 0, stream>>>(dx, w_s, w_r, w_g, ws);
    fused_kernel<<<BB * CC, 256, 0, stream>>>(
        dx, gamma, beta, w_t, b_t, b_s, b_r, b_g, ws, out);
}

// Round 11
// 65.003 us; speedup vs baseline: 1.7187x; 1.0166x over previous
//
#include <hip/hip_runtime.h>
#include <math.h>

// Problem constants (match reference)
#define BB   16
#define CC   64
#define LL   512
#define LP   16
#define DM   1024
#define NP   64
#define PRD  256   // period = L/2
#define HEAD 128   // PRD/2
#define NV   256   // L - PRD

typedef float f32x4 __attribute__((ext_vector_type(4)));

// workspace layout (in floats); all offsets 16B-aligned
#define OFF_MEANP 0                       // 8192
#define OFF_WSF   8192                    // 16*256 folded seasonal weights
#define OFF_WRS   12288                   // 16 resid weight sums
#define OFF_WGT   12304                   // 48*1024 transposed w_g

// ---------------------------------------------------------------------------
// Kernel 1: blocks 0..31 = per-(b,l) channel stats; block 32 = weight folding;
// blocks 33..48 = w_g transpose ([1024][48] -> [48][1024]). (identical to R10)
// ---------------------------------------------------------------------------
__global__ __launch_bounds__(256) void statsprep_kernel(
    const float* __restrict__ dx, const float* __restrict__ w_s,
    const float* __restrict__ w_r, const float* __restrict__ w_g,
    float* __restrict__ ws)
{
    const int tid = threadIdx.x, bid = blockIdx.x;
    if (bid < 32) {
        int id = bid * 256 + tid;            // 0..8191
        int b = id >> 9, l = id & 511;
        const float* p = dx + (size_t)b * CC * LL + l;
        float s = 0.f, sq = 0.f;
#pragma unroll 8
        for (int c = 0; c < CC; ++c) {
            float v = p[(size_t)c * LL];
            s += v; sq += v * v;
        }
        float mean = s * (1.0f / CC);
        float var  = (sq - (float)CC * mean * mean) * (1.0f / (CC - 1));
        ws[OFF_MEANP + id] = mean / sqrtf(var);
    } else if (bid == 32) {
        // fold seasonal weights: wsf[g][m] = w_s[g][m] + w_s[g][m+256]
#pragma unroll
        for (int idx = tid; idx < 16 * PRD; idx += 256) {
            int g = idx >> 8, m = idx & 255;
            ws[OFF_WSF + idx] = w_s[g * LL + m] + w_s[g * LL + PRD + m];
        }
        // resid weight sums: wrs[g] = sum w_r[g][128:384]
        int g = tid >> 4, ln = tid & 15;
        float s = 0.f;
        for (int k = ln; k < PRD; k += 16) s += w_r[g * LL + HEAD + k];
#pragma unroll
        for (int m = 8; m; m >>= 1) s += __shfl_xor(s, m, 16);
        if (ln == 0) ws[OFF_WRS + g] = s;
    } else {
        // transpose w_g: wgt[j*1024 + d] = w_g[d*48 + j]
        int base = (bid - 33) * 3072 + tid;
#pragma unroll
        for (int k = 0; k < 12; ++k) {
            int e = base + k * 256;          // e = j*1024 + d
            int j = e >> 10, d = e & 1023;
            ws[OFF_WGT + e] = w_g[d * 48 + j];
        }
    }
}

// ---------------------------------------------------------------------------
// Kernel 2 (fused): one block per (b,c). Transform -> scan decompose ->
// 48 features (LDS) -> matvec vs TRANSPOSED w_g (coalesced, L2-hot) ->
// stage 4KB row in LDS -> per-WAVE contiguous 64KB store streams.
// ---------------------------------------------------------------------------
__global__ __launch_bounds__(256) void fused_kernel(
    const float* __restrict__ dx,    const float* __restrict__ gamma,
    const float* __restrict__ beta,  const float* __restrict__ w_t,
    const float* __restrict__ b_t,   const float* __restrict__ b_s,
    const float* __restrict__ b_r,   const float* __restrict__ b_g,
    const float* __restrict__ ws,    float* __restrict__ out)
{
    __shared__ __align__(16) float xs[LL];
    __shared__ __align__(16) float pps[LL/2 + 1];
    __shared__ __align__(16) float tvs[NV];
    __shared__ __align__(16) float pas[PRD];
    __shared__ __align__(16) float feats[48];
    __shared__ __align__(16) float sres[DM];      // 4KB result row
    __shared__ float wsum[4];
    __shared__ float wred[4];

    const int tid  = threadIdx.x;
    const int lane = tid & 63;
    const int wv   = tid >> 6;
    const int bc   = blockIdx.x;
    const int b    = bc >> 6;

    // transform (float2): x = gamma*(dx - meanp) + beta
    const size_t base = (size_t)bc * LL;
    float2 xv = ((const float2*)(dx    + base))[tid];
    float2 gv = ((const float2*)(gamma + base))[tid];
    float2 bv = ((const float2*)(beta  + base))[tid];
    float2 mv = ((const float2*)(ws + OFF_MEANP + (size_t)b * LL))[tid];
    float2 xp;
    xp.x = gv.x * (xv.x - mv.x) + bv.x;
    xp.y = gv.y * (xv.y - mv.y) + bv.y;
    ((float2*)xs)[tid] = xp;

    // inclusive scan of pair-sums (256 pairs)
    float v = xp.x + xp.y;
#pragma unroll
    for (int d = 1; d < 64; d <<= 1) {
        float t = __shfl_up(v, d, 64);
        if (lane >= d) v += t;
    }
    if (lane == 63) wsum[wv] = v;
    __syncthreads();
    float off = 0.f;
    for (int w = 0; w < wv; ++w) off += wsum[w];
    pps[tid + 1] = v + off;
    if (tid == 0) pps[0] = 0.f;
    __syncthreads();

    // trend via prefix sums
    const int i  = tid;
    const int k2 = i + 257;
    const float Pi = pps[i  >> 1] + ((i  & 1) ? xs[i  & ~1] : 0.f);
    const float Pk = pps[k2 >> 1] + ((k2 & 1) ? xs[k2 & ~1] : 0.f);
    const float tv = (Pk - Pi - 0.5f * (xs[i] + xs[i + 256])) * (1.0f / 256.0f);
    tvs[i] = tv;
    const float dv = xs[HEAD + i] - tv;

    // mdv = mean(dv)
    float r = dv;
#pragma unroll
    for (int m = 32; m; m >>= 1) r += __shfl_xor(r, m, 64);
    if (lane == 0) wred[wv] = r;
    __syncthreads();
    const float mdv = (wred[0] + wred[1] + wred[2] + wred[3]) * (1.0f / 256.0f);

    pas[(i + 128) & 255] = dv - mdv;
    __syncthreads();

    // feature dots with folded weights (8 float4 loads/thread)
    {
        const int g  = tid >> 4;
        const int ln = tid & 15;
        const f32x4* wt4  = (const f32x4*)(w_t + g * LL + HEAD);
        const f32x4* wsf4 = (const f32x4*)(ws + OFF_WSF + g * PRD);
        const f32x4* tv4  = (const f32x4*)tvs;
        const f32x4* pa4  = (const f32x4*)pas;
        float at = 0.f, as = 0.f;
#pragma unroll
        for (int q = 0; q < 4; ++q) {
            const int m = ln * 4 + q;
            f32x4 t = tv4[m], p = pa4[m];
            f32x4 a = wt4[m], sfw = wsf4[m];
            at += t.x * a.x + t.y * a.y + t.z * a.z + t.w * a.w;
            as += p.x * sfw.x + p.y * sfw.y + p.z * sfw.z + p.w * sfw.w;
        }
#pragma unroll
        for (int msk = 8; msk; msk >>= 1) {
            at += __shfl_xor(at, msk, 64);
            as += __shfl_xor(as, msk, 64);
        }
        if (ln == 0) {
            feats[g]      = at + b_t[g];
            feats[16 + g] = as + b_s[g];
            feats[32 + g] = mdv * ws[OFF_WRS + g] + b_r[g];
        }
    }
    __syncthreads();

    // ---- matvec vs transposed w_g: thread handles d = q*256+tid, q=0..3.
    const float* wT = ws + OFF_WGT;
    float acc0 = b_g[tid];
    float acc1 = b_g[256 + tid];
    float acc2 = b_g[512 + tid];
    float acc3 = b_g[768 + tid];
#pragma unroll
    for (int j = 0; j < 48; ++j) {
        const float fj = feats[j];
        const float* w = wT + j * DM + tid;
        acc0 = fmaf(fj, w[0],   acc0);
        acc1 = fmaf(fj, w[256], acc1);
        acc2 = fmaf(fj, w[512], acc2);
        acc3 = fmaf(fj, w[768], acc3);
    }
    sres[tid]       = acc0;
    sres[256 + tid] = acc1;
    sres[512 + tid] = acc2;
    sres[768 + tid] = acc3;
    __syncthreads();

    // ---- broadcast stores, per-wave CONTIGUOUS 64KB streams.
    // Wave wv owns rows [wv*16, wv*16+16). Each lane holds all 4 row-parts
    // in registers; consecutive wave-instrs advance by exactly 1KB.
    const f32x4* s4 = (const f32x4*)sres;
    const f32x4 v0 = s4[lane];
    const f32x4 v1 = s4[64 + lane];
    const f32x4 v2 = s4[128 + lane];
    const f32x4 v3 = s4[192 + lane];
    f32x4* op = (f32x4*)out + (size_t)bc * (NP * DM / 4)
              + (size_t)(wv * 16) * (DM / 4) + lane;
#pragma unroll
    for (int n = 0; n < 16; ++n) {
        op[n * (DM / 4) +   0] = v0;
        op[n * (DM / 4) +  64] = v1;
        op[n * (DM / 4) + 128] = v2;
        op[n * (DM / 4) + 192] = v3;
    }
}

// ---------------------------------------------------------------------------
extern "C" void kernel_launch(void* const* d_in, const int* in_sizes, int n_in,
                              void* d_out, int out_size, void* d_ws, size_t ws_size,
                              hipStream_t stream) {
    const float* dx    = (const float*)d_in[0];
    const float* gamma = (const float*)d_in[1];
    const float* beta  = (const float*)d_in[2];
    const float* w_t   = (const float*)d_in[3];
    const float* b_t   = (const float*)d_in[4];
    const float* w_s   = (const float*)d_in[5];
    const float* b_s   = (const float*)d_in[6];
    const float* w_r   = (const float*)d_in[7];
    const float* b_r   = (const float*)d_in[8];
    const float* w_g   = (const float*)d_in[9];
    const float* b_g   = (const float*)d_in[10];
    float* out = (float*)d_out;
    float* ws  = (float*)d_ws;

    statsprep_kernel<<<49, 256, 0, stream>>>(dx, w_s, w_r, w_g, ws);
    fused_kernel<<<BB * CC, 256, 0, stream>>>(
        dx, gamma, beta, w_t, b_t, b_s, b_r, b_g, ws, out);
}